// Round 6
// baseline (3471.764 us; speedup 1.0000x reference)
//
#include <hip/hip_runtime.h>

typedef __bf16 bf16;
typedef __bf16 bf16x4 __attribute__((ext_vector_type(4)));
typedef __bf16 bf16x8 __attribute__((ext_vector_type(8)));
typedef float  f32x4  __attribute__((ext_vector_type(4)));
typedef unsigned long long u64;
typedef unsigned int u32;

#define MFMA(a,b,c) __builtin_amdgcn_mfma_f32_16x16x32_bf16((a),(b),(c),0,0,0)

// Problem dims
#define TSTEPS 512
#define NBATCH 128
#define DIN    256
#define DH     1024
#define NRANK  128
#define DOUT   256

// Scan decomposition: 8 batch-groups x 4 hidden-groups = 32 WGs (round-2 proven).
#define NBG 8
#define NGH 4

// bf16 sentinel: non-canonical NaN payload. Finite bf16 arithmetic (MFMA sums of
// finite products, relu'd h, finite U/V) can produce +-inf (0x7F80) but never a
// NaN with payload 0x41 — conversions of non-NaN fp32 never yield it.
#define SENTH  0x7FC1ull
#define SENT64 0x7FC17FC17FC17FC1ull

// Workspace layout (bytes) — identical footprint to previous rounds.
#define ZI_OFF    0ull               // bf16 [512*128*1024]  = 134217728 B
#define QSEQ_OFF  134217728ull       // bf16 [512*128*128]   =  16777216 B
#define PBUF_OFF  150994944ull       // legacy (unused this round)
#define FLAG_OFF  (PBUF_OFF + 262144ull)
#define WIN_OFF   151519232ull       // bf16 [1024*256] = 524288 B; DEAD after k_zi ->
                                     // reused as sentinel-tagged partial slots
                                     // [3 slot][8 bg][4 g][512] u64 = 393216 B.
#define U_OFF     152043520ull       // bf16 [128*1024]
#define V_OFF     152305664ull       // bf16 [1024*128]
#define WOUT_OFF  152567808ull       // bf16 [256*1024]
#define BAR_OFF   153092096ull       // legacy (unused)

// Coherent (agent-scope, cache-bypassing) 8-byte access helpers (proven pattern).
__device__ __forceinline__ void cstore64(u64* p, u64 v) {
  __hip_atomic_store(p, v, __ATOMIC_RELAXED, __HIP_MEMORY_SCOPE_AGENT);
}
__device__ __forceinline__ u64 cload64(const u64* p) {
  return __hip_atomic_load(p, __ATOMIC_RELAXED, __HIP_MEMORY_SCOPE_AGENT);
}
__device__ __forceinline__ float bfbits(u32 hs) {
  return __builtin_bit_cast(float, hs << 16);
}
__device__ __forceinline__ bool issent(u64 v) {
  return ((v & 0xFFFFull) == SENTH) | (((v >> 16) & 0xFFFFull) == SENTH) |
         (((v >> 32) & 0xFFFFull) == SENTH) | ((v >> 48) == SENTH);
}
union B4U { u64 u; bf16x4 b; };

// LDS-only barrier: leaves VMEM (publish stores / zi prefetch) in flight.
#define BAR_LGKM() do { \
  asm volatile("s_waitcnt lgkmcnt(0)" ::: "memory"); \
  __builtin_amdgcn_sched_barrier(0); \
  __builtin_amdgcn_s_barrier(); \
  __builtin_amdgcn_sched_barrier(0); \
} while (0)

// ---------------------------------------------------------------- K0: prep (unchanged)
__global__ __launch_bounds__(256) void k_prep(const float* __restrict__ W_in,
                                              const float* __restrict__ U,
                                              const float* __restrict__ V,
                                              const float* __restrict__ W_out,
                                              char* __restrict__ ws) {
  bf16* winb  = (bf16*)(ws + WIN_OFF);
  bf16* ub    = (bf16*)(ws + U_OFF);
  bf16* vb    = (bf16*)(ws + V_OFF);
  bf16* woutb = (bf16*)(ws + WOUT_OFF);
  bf16* qseq  = (bf16*)(ws + QSEQ_OFF);
  unsigned* flg = (unsigned*)(ws + FLAG_OFF);
  size_t id = (size_t)blockIdx.x * 256 + threadIdx.x;
  if      (id < 262144) winb[id]           = (bf16)W_in[id];
  else if (id < 393216) ub[id - 262144]    = (bf16)U[id - 262144];
  else if (id < 524288) vb[id - 393216]    = (bf16)V[id - 393216];
  else if (id < 786432) woutb[id - 524288] = (bf16)W_out[id - 524288];
  else if (id < 802816) qseq[id - 786432]  = (bf16)0.0f;   // q_0 = 0
  else if (id < 802848) flg[id - 802816]   = 0u;           // legacy
}

// ---------------------------------------------------------------- K1: zi = x @ W_in^T  (unchanged)
__global__ __launch_bounds__(256) void k_zi(const float* __restrict__ x,
                                            const char* __restrict__ ws,
                                            bf16* __restrict__ zi) {
  const bf16* winb = (const bf16*)(ws + WIN_OFF);
  __shared__ bf16 xl[128 * 264];
  __shared__ bf16 wl[128 * 264];
  const int tid = threadIdx.x, lane = tid & 63, wv = tid >> 6;
  const int q4 = lane >> 4, l16 = lane & 15;
  const int m0b = blockIdx.x * 128, n0 = blockIdx.y * 128;

  for (int ch = tid; ch < 8192; ch += 256) {
    int r = ch >> 6, c4 = ch & 63;
    float4 f = *(const float4*)&x[(size_t)(m0b + r) * 256 + c4 * 4];
    bf16x4 b; b[0] = (bf16)f.x; b[1] = (bf16)f.y; b[2] = (bf16)f.z; b[3] = (bf16)f.w;
    *(bf16x4*)&xl[r * 264 + c4 * 4] = b;
  }
  for (int ch = tid; ch < 4096; ch += 256) {
    int r = ch >> 5, c8 = ch & 31;
    *(uint4*)&wl[r * 264 + c8 * 8] = *(const uint4*)&winb[(size_t)(n0 + r) * 256 + c8 * 8];
  }
  __syncthreads();

  f32x4 z4 = {0.f, 0.f, 0.f, 0.f};
  f32x4 acc[2][8];
#pragma unroll
  for (int i = 0; i < 2; i++)
#pragma unroll
    for (int j = 0; j < 8; j++) acc[i][j] = z4;

  const int m0 = wv * 32;
#pragma unroll
  for (int kc = 0; kc < 8; kc++) {
    bf16x8 a0 = *(bf16x8*)&xl[(m0 + l16) * 264 + kc * 32 + q4 * 8];
    bf16x8 a1 = *(bf16x8*)&xl[(m0 + 16 + l16) * 264 + kc * 32 + q4 * 8];
#pragma unroll
    for (int nt = 0; nt < 8; nt++) {
      bf16x8 b = *(bf16x8*)&wl[(nt * 16 + l16) * 264 + kc * 32 + q4 * 8];
      acc[0][nt] = MFMA(a0, b, acc[0][nt]);
      acc[1][nt] = MFMA(a1, b, acc[1][nt]);
    }
  }
  __syncthreads();
#pragma unroll
  for (int mt = 0; mt < 2; mt++)
#pragma unroll
    for (int nt = 0; nt < 8; nt++)
#pragma unroll
      for (int r = 0; r < 4; r++) {
        int m = m0 + mt * 16 + q4 * 4 + r;
        int c = nt * 16 + l16;
        xl[m * 136 + c] = (bf16)acc[mt][nt][r];
      }
  __syncthreads();
  for (int ch = tid; ch < 2048; ch += 256) {
    int r = ch >> 4, c8 = ch & 15;
    *(uint4*)&zi[(size_t)(m0b + r) * 1024 + n0 + c8 * 8] = *(uint4*)&xl[r * 136 + c8 * 8];
  }
}

// ---------------------------------------------------------------- K1b: sentinel-fill partial slots
// Runs after k_zi (W_in region dead), before k_scan. 192 blocks x 256 = 49152 u64 = 384 KB.
__global__ __launch_bounds__(256) void k_clr(char* __restrict__ ws) {
  u64* tp = (u64*)(ws + WIN_OFF);
  tp[(size_t)blockIdx.x * 256 + threadIdx.x] = SENT64;
}

// ---------------------------------------------------------------- K2: scan, sentinel protocol
// 32 WGs (bg,g): rows [bg*16,+16), h-cols [g*256,+256). Weights LDS-resident.
// Per step t (computing q(t+1)):
//   vmcnt(0)            (drains prev publish+clear BEFORE this step's publish issues)
//   prefetch zi(t+1)
//   stage2 TRANSPOSED: zh^T[hcol][batch] = V_g @ q_t^T ; h = relu(+b+zi) -> hl (b64 writes)
//   BAR | stage1 TRANSPOSED: P[rank][batch] = U_g @ h^T -> accumulators
//   publish slot (t+1)%3 (fire-and-forget coherent stores, coalesced layout)
//   reduce: spin on the 4 partials' DATA until sentinel-free (loads ARE the poll), sum
//   install q(t+1) -> ql (+ qseq by g==0)
//   re-sentinel own slot t%3 (spin success proved all siblings consumed q(t))
//   BAR
// Slot t%3 is rewritten at publish(t+3): clear drains at t+1's vmcnt before
// publish(t+2) issues, and any sibling reading for t+3 has already observed
// publish(t+2) -> never sees stale data. No flags, no drain-before-flag.
__global__ __launch_bounds__(256) void k_scan(char* __restrict__ ws,
                                              const float* __restrict__ b_h) {
  const bf16* zi = (const bf16*)(ws + ZI_OFF);
  const bf16* ub = (const bf16*)(ws + U_OFF);
  const bf16* vb = (const bf16*)(ws + V_OFF);
  bf16* qseq = (bf16*)(ws + QSEQ_OFF);
  u64* tpb = (u64*)(ws + WIN_OFF);               // [3 slot][8 bg][4 g][512] u64

  __shared__ bf16 Vl[256 * 136];   // V[hcol0+r][rank]   69632 B
  __shared__ bf16 Ul[128 * 264];   // U[rank][hcol0+c]   67584 B
  __shared__ bf16 ql[16 * 136];    // q_t [row][rank]     4352 B
  __shared__ bf16 hl[16 * 264];    // h   [row][hcol]     8448 B
  // total 150016 B

  const int tid = threadIdx.x, lane = tid & 63, w = tid >> 6;   // 4 waves
  const int l16 = lane & 15, q4 = lane >> 4;
  const int bg = blockIdx.x & 7, g = blockIdx.x >> 3;
  const int brow0 = bg * 16, hcol0 = g * 256;

  // ---- stage weights (one-time, L2 -> LDS)
  for (int ch = tid; ch < 4096; ch += 256) {
    int r = ch >> 4, c8 = ch & 15;
    *(uint4*)&Vl[r * 136 + c8 * 8] = *(const uint4*)&vb[(size_t)(hcol0 + r) * 128 + c8 * 8];
  }
  for (int ch = tid; ch < 4096; ch += 256) {
    int r = ch >> 5, c8 = ch & 31;
    *(uint4*)&Ul[r * 264 + c8 * 8] = *(const uint4*)&ub[(size_t)r * 1024 + hcol0 + c8 * 8];
  }
  for (int i = tid; i < 16 * 136; i += 256) ql[i] = (bf16)0.0f;   // q_0 = 0

  // bias at stage2-transposed C-frag positions: hcol = w*64 + nt*16 + q4*4 + rr
  float bj[16];
#pragma unroll
  for (int nt = 0; nt < 4; nt++)
#pragma unroll
    for (int rr = 0; rr < 4; rr++)
      bj[nt * 4 + rr] = b_h[hcol0 + w * 64 + nt * 16 + q4 * 4 + rr];

  // zi at stage2-transposed C-frag positions: row = brow0+l16, 4 consecutive cols -> u64
  B4U zc[4], zn[4];
#pragma unroll
  for (int nt = 0; nt < 4; nt++)
    zc[nt].u = *(const u64*)&zi[(size_t)(brow0 + l16) * 1024 + hcol0 + w * 64 + nt * 16 + q4 * 4];
  __syncthreads();

  const f32x4 z4 = {0.f, 0.f, 0.f, 0.f};

  for (int t = 0; t < TSTEPS - 1; t++) {
    // drain prev-step publish + clear stores (and long-done loads) BEFORE issuing
    // this step's stores — provides the clear->publish visibility ordering.
    asm volatile("s_waitcnt vmcnt(0)" ::: "memory");
    __builtin_amdgcn_sched_barrier(0);

    // prefetch zi[t+1] (plain cached u64 loads; consumed at step end)
#pragma unroll
    for (int nt = 0; nt < 4; nt++)
      zn[nt].u = *(const u64*)&zi[((size_t)(t + 1) * NBATCH + brow0 + l16) * 1024 +
                                  hcol0 + w * 64 + nt * 16 + q4 * 4];

    // ---- stage2 (TRANSPOSED): zh^T[hcol][batch] = V_g @ q_t^T  (K=128)
    // A = V rows = hcol (w*64+nt*16+l16), B = q rows = batch (l16).
    // C: col = batch l16, rows = hcol w*64+nt*16+q4*4+rr (4 consecutive hcols).
    f32x4 az[4] = {z4, z4, z4, z4};
#pragma unroll
    for (int kc = 0; kc < 4; kc++) {
      bf16x8 qf = *(const bf16x8*)&ql[l16 * 136 + kc * 32 + q4 * 8];
#pragma unroll
      for (int nt = 0; nt < 4; nt++) {
        bf16x8 vf = *(const bf16x8*)&Vl[(w * 64 + nt * 16 + l16) * 136 + kc * 32 + q4 * 8];
        az[nt] = MFMA(vf, qf, az[nt]);
      }
    }
    // h = relu(zh + b + zi): 4 consecutive hcols -> one ds_write_b64 per nt
#pragma unroll
    for (int nt = 0; nt < 4; nt++) {
      bf16x4 hv;
#pragma unroll
      for (int rr = 0; rr < 4; rr++) {
        float v = az[nt][rr] + bj[nt * 4 + rr] + (float)zc[nt].b[rr];
        hv[rr] = (bf16)fmaxf(v, 0.0f);
      }
      *(bf16x4*)&hl[l16 * 264 + w * 64 + nt * 16 + q4 * 4] = hv;
    }
    BAR_LGKM();   // hl ready; ql fully consumed

    // ---- stage1 (TRANSPOSED): P[rank][batch] = U_slice @ h^T  (K=256)
    // A = U rows = rank (w*32+mt*16+l16), B = h rows = batch (l16).
    // C: col = batch l16, rows = rank w*32+mt*16+q4*4+rr (4 consecutive ranks).
    f32x4 ap[2] = {z4, z4};
#pragma unroll
    for (int kc = 0; kc < 8; kc++) {
      bf16x8 hf = *(const bf16x8*)&hl[l16 * 264 + kc * 32 + q4 * 8];
#pragma unroll
      for (int mt = 0; mt < 2; mt++) {
        bf16x8 uf = *(const bf16x8*)&Ul[(w * 32 + mt * 16 + l16) * 264 + kc * 32 + q4 * 8];
        ap[mt] = MFMA(uf, hf, ap[mt]);
      }
    }

    // ---- publish partial (fire-and-forget) to slot (t+1)%3
    const int s1 = (t + 1) % 3;
    u64* myp = &tpb[(size_t)((s1 * NBG + bg) * NGH + g) * 512];
#pragma unroll
    for (int mt = 0; mt < 2; mt++) {
      B4U pk;
      pk.b[0] = (bf16)ap[mt][0]; pk.b[1] = (bf16)ap[mt][1];
      pk.b[2] = (bf16)ap[mt][2]; pk.b[3] = (bf16)ap[mt][3];
      cstore64(&myp[l16 * 32 + w * 8 + mt * 4 + q4], pk.u);
    }

    // ---- reduce: spin on data (loads ARE the poll). Thread owns row tid>>4,
    // ranks [(tid&15)*8,+8): 2 coalesced u64 per partial.
    const u64* rb = &tpb[(size_t)(s1 * NBG + bg) * NGH * 512];
    u64 vv[8];
#pragma unroll
    for (int pp = 0; pp < 4; pp++) {
      vv[pp * 2]     = cload64(&rb[(size_t)pp * 512 + tid * 2]);
      vv[pp * 2 + 1] = cload64(&rb[(size_t)pp * 512 + tid * 2 + 1]);
    }
#pragma unroll
    for (int pp = 0; pp < 4; pp++)
#pragma unroll
      for (int i = 0; i < 2; i++)
        while (issent(vv[pp * 2 + i]))
          vv[pp * 2 + i] = cload64(&rb[(size_t)pp * 512 + tid * 2 + i]);

    float s[8] = {0.f, 0.f, 0.f, 0.f, 0.f, 0.f, 0.f, 0.f};
#pragma unroll
    for (int pp = 0; pp < 4; pp++)
#pragma unroll
      for (int i = 0; i < 2; i++) {
        u64 u = vv[pp * 2 + i];
        s[i * 4 + 0] += bfbits((u32)(u & 0xFFFFu));
        s[i * 4 + 1] += bfbits((u32)((u >> 16) & 0xFFFFu));
        s[i * 4 + 2] += bfbits((u32)((u >> 32) & 0xFFFFu));
        s[i * 4 + 3] += bfbits((u32)(u >> 48));
      }

    // ---- install q_{t+1} into ql (+ qseq by g==0)
    union { bf16x8 v; uint4 u4; } qv;
#pragma unroll
    for (int k = 0; k < 8; k++) qv.v[k] = (bf16)s[k];
    *(bf16x8*)&ql[(tid >> 4) * 136 + (tid & 15) * 8] = qv.v;
    if (g == 0)
      *(uint4*)&qseq[((size_t)(t + 1) * NBATCH + brow0 + (tid >> 4)) * NRANK + (tid & 15) * 8] = qv.u4;

    // ---- re-sentinel own slot t%3 (spin success proved all consumed q(t)).
    // Drained by next step's vmcnt(0) before publish(t+2) issues; slot reused at t+3.
    const int s0 = t % 3;
    u64* myc = &tpb[(size_t)((s0 * NBG + bg) * NGH + g) * 512];
    cstore64(&myc[tid * 2],     SENT64);
    cstore64(&myc[tid * 2 + 1], SENT64);

    BAR_LGKM();   // ql ready for next stage2; hl free for overwrite

#pragma unroll
    for (int nt = 0; nt < 4; nt++) zc[nt] = zn[nt];
  }
}

// ---------------------------------------------------------------- K3: hidden[t] = relu(q_t V^T + b + zi_t)  (unchanged)
__global__ __launch_bounds__(256) void k_hidden(const char* __restrict__ ws,
                                                const float* __restrict__ b_h,
                                                float* __restrict__ hid) {
  const bf16* qseq = (const bf16*)(ws + QSEQ_OFF);
  const bf16* vb   = (const bf16*)(ws + V_OFF);
  const bf16* zi   = (const bf16*)(ws + ZI_OFF);
  const int t = blockIdx.x, n0 = blockIdx.y * 128;
  const int tid = threadIdx.x, lane = tid & 63, wv = tid >> 6;
  const int q4 = lane >> 4, l16 = lane & 15;

  __shared__ bf16 ql2[128 * 136];
  __shared__ bf16 vl2[128 * 136];
  __shared__ bf16 zl2[128 * 136];
  __shared__ float bl2[128];

  for (int ch = tid; ch < 2048; ch += 256) {
    int r = ch >> 4, c8 = ch & 15;
    *(uint4*)&ql2[r * 136 + c8 * 8] = *(const uint4*)&qseq[(size_t)t * 16384 + r * 128 + c8 * 8];
    *(uint4*)&vl2[r * 136 + c8 * 8] = *(const uint4*)&vb[(size_t)(n0 + r) * 128 + c8 * 8];
    *(uint4*)&zl2[r * 136 + c8 * 8] = *(const uint4*)&zi[((size_t)t * 128 + r) * 1024 + n0 + c8 * 8];
  }
  if (tid < 128) bl2[tid] = b_h[n0 + tid];
  __syncthreads();

  f32x4 z4 = {0.f, 0.f, 0.f, 0.f};
  f32x4 acc[2][8];
#pragma unroll
  for (int i = 0; i < 2; i++)
#pragma unroll
    for (int j = 0; j < 8; j++) acc[i][j] = z4;

  const int m0 = wv * 32;
#pragma unroll
  for (int kc = 0; kc < 4; kc++) {
    bf16x8 a0 = *(bf16x8*)&ql2[(m0 + l16) * 136 + kc * 32 + q4 * 8];
    bf16x8 a1 = *(bf16x8*)&ql2[(m0 + 16 + l16) * 136 + kc * 32 + q4 * 8];
#pragma unroll
    for (int nt = 0; nt < 8; nt++) {
      bf16x8 b = *(bf16x8*)&vl2[(nt * 16 + l16) * 136 + kc * 32 + q4 * 8];
      acc[0][nt] = MFMA(a0, b, acc[0][nt]);
      acc[1][nt] = MFMA(a1, b, acc[1][nt]);
    }
  }
#pragma unroll
  for (int mt = 0; mt < 2; mt++)
#pragma unroll
    for (int nt = 0; nt < 8; nt++)
#pragma unroll
      for (int r = 0; r < 4; r++) {
        int m = m0 + mt * 16 + q4 * 4 + r;
        int c = nt * 16 + l16;
        float v = acc[mt][nt][r] + bl2[c] + (float)zl2[m * 136 + c];
        hid[((size_t)t * 128 + m) * 1024 + n0 + c] = fmaxf(v, 0.0f);
      }
}

// ---------------------------------------------------------------- K4: output = hidden @ W_out^T + b_out (unchanged)
__global__ __launch_bounds__(512) void k_out(const char* __restrict__ ws,
                                             const float* __restrict__ hid,
                                             const float* __restrict__ b_out,
                                             float* __restrict__ out) {
  const bf16* woutb = (const bf16*)(ws + WOUT_OFF);
  const int t = blockIdx.x;
  const int tid = threadIdx.x, lane = tid & 63, wv = tid >> 6;  // 8 waves
  const int q4 = lane >> 4, l16 = lane & 15;

  __shared__ bf16 hl2[128 * 136];
  __shared__ bf16 wl2[256 * 136];
  __shared__ float bol[256];
  if (tid < 256) bol[tid] = b_out[tid];

  f32x4 z4 = {0.f, 0.f, 0.f, 0.f};
  f32x4 acc[16];
#pragma unroll
  for (int j = 0; j < 16; j++) acc[j] = z4;

  const int m0 = wv * 16;
  for (int k0 = 0; k0 < 1024; k0 += 128) {
    __syncthreads();
    for (int ch = tid; ch < 4096; ch += 512) {
      int r = ch >> 5, c4 = ch & 31;
      float4 f = *(const float4*)&hid[((size_t)t * 128 + r) * 1024 + k0 + c4 * 4];
      bf16x4 b; b[0] = (bf16)f.x; b[1] = (bf16)f.y; b[2] = (bf16)f.z; b[3] = (bf16)f.w;
      *(bf16x4*)&hl2[r * 136 + c4 * 4] = b;
    }
    for (int ch = tid; ch < 4096; ch += 512) {
      int r = ch >> 4, c8 = ch & 15;
      *(uint4*)&wl2[r * 136 + c8 * 8] = *(const uint4*)&woutb[(size_t)r * 1024 + k0 + c8 * 8];
    }
    __syncthreads();
#pragma unroll
    for (int kc = 0; kc < 4; kc++) {
      bf16x8 a = *(bf16x8*)&hl2[(m0 + l16) * 136 + kc * 32 + q4 * 8];
#pragma unroll
      for (int nt = 0; nt < 16; nt++) {
        bf16x8 b = *(bf16x8*)&wl2[(nt * 16 + l16) * 136 + kc * 32 + q4 * 8];
        acc[nt] = MFMA(a, b, acc[nt]);
      }
    }
  }
#pragma unroll
  for (int nt = 0; nt < 16; nt++)
#pragma unroll
    for (int r = 0; r < 4; r++) {
      int m = m0 + q4 * 4 + r;
      int c = nt * 16 + l16;
      out[((size_t)t * 128 + m) * 256 + c] = acc[nt][r] + bol[c];
    }
}

// ---------------------------------------------------------------- launch
extern "C" void kernel_launch(void* const* d_in, const int* in_sizes, int n_in,
                              void* d_out, int out_size, void* d_ws, size_t ws_size,
                              hipStream_t stream) {
  (void)in_sizes; (void)n_in; (void)out_size; (void)ws_size;
  const float* x     = (const float*)d_in[0];
  const float* W_in  = (const float*)d_in[1];
  const float* U     = (const float*)d_in[2];
  const float* V     = (const float*)d_in[3];
  const float* b_h   = (const float*)d_in[4];
  const float* W_out = (const float*)d_in[5];
  const float* b_out = (const float*)d_in[6];
  char* ws = (char*)d_ws;
  float* hid = (float*)d_out;
  float* out = hid + (size_t)TSTEPS * NBATCH * DH;
  bf16* zi = (bf16*)(ws + ZI_OFF);

  k_prep<<<dim3(3137), dim3(256), 0, stream>>>(W_in, U, V, W_out, ws);
  k_zi<<<dim3(512, 8), dim3(256), 0, stream>>>(x, ws, zi);
  k_clr<<<dim3(192), dim3(256), 0, stream>>>(ws);
  k_scan<<<dim3(NBG * NGH), dim3(256), 0, stream>>>(ws, b_h);
  k_hidden<<<dim3(512, 8), dim3(256), 0, stream>>>(ws, b_h, hid);
  k_out<<<dim3(512), dim3(512), 0, stream>>>(ws, hid, b_out, out);
}

// Round 7
// 2899.034 us; speedup vs baseline: 1.1976x; 1.1976x over previous
//
#include <hip/hip_runtime.h>

typedef __bf16 bf16;
typedef __bf16 bf16x4 __attribute__((ext_vector_type(4)));
typedef __bf16 bf16x8 __attribute__((ext_vector_type(8)));
typedef float  f32x4  __attribute__((ext_vector_type(4)));
typedef unsigned long long u64;
typedef unsigned int u32;

#define MFMA(a,b,c) __builtin_amdgcn_mfma_f32_16x16x32_bf16((a),(b),(c),0,0,0)

// Problem dims
#define TSTEPS 512
#define NBATCH 128
#define DIN    256
#define DH     1024
#define NRANK  128
#define DOUT   256

// Scan decomposition: 8 batch-groups x 4 hidden-groups = 32 WGs (round-2 proven).
#define NBG 8
#define NGH 4

// bf16 sentinel: non-canonical NaN payload. Finite bf16 arithmetic (MFMA sums of
// finite products, relu'd h, finite U/V) can produce +-inf (0x7F80) but never a
// NaN with payload 0x41 — conversions of non-NaN fp32 never yield it.
#define SENTH  0x7FC1ull
#define SENT64 0x7FC17FC17FC17FC1ull

// Workspace layout (bytes) — identical footprint to previous rounds.
#define ZI_OFF    0ull               // bf16 [512*128*1024]  = 134217728 B
#define QSEQ_OFF  134217728ull       // bf16 [512*128*128]   =  16777216 B
#define PBUF_OFF  150994944ull       // legacy (unused this round)
#define FLAG_OFF  (PBUF_OFF + 262144ull)
#define WIN_OFF   151519232ull       // bf16 [1024*256] = 524288 B; DEAD after k_zi ->
                                     // reused as sentinel-tagged partial slots
                                     // [3 slot][8 bg][4 g][512] u64 = 393216 B.
#define U_OFF     152043520ull       // bf16 [128*1024]
#define V_OFF     152305664ull       // bf16 [1024*128]
#define WOUT_OFF  152567808ull       // bf16 [256*1024]
#define BAR_OFF   153092096ull       // legacy (unused)

// Coherent (agent-scope, cache-bypassing) 8-byte access helpers (proven pattern).
__device__ __forceinline__ void cstore64(u64* p, u64 v) {
  __hip_atomic_store(p, v, __ATOMIC_RELAXED, __HIP_MEMORY_SCOPE_AGENT);
}
__device__ __forceinline__ u64 cload64(const u64* p) {
  return __hip_atomic_load(p, __ATOMIC_RELAXED, __HIP_MEMORY_SCOPE_AGENT);
}
__device__ __forceinline__ float bfbits(u32 hs) {
  return __builtin_bit_cast(float, hs << 16);
}
__device__ __forceinline__ bool issent(u64 v) {
  return ((v & 0xFFFFull) == SENTH) | (((v >> 16) & 0xFFFFull) == SENTH) |
         (((v >> 32) & 0xFFFFull) == SENTH) | ((v >> 48) == SENTH);
}
union B4U { u64 u; bf16x4 b; };

// LDS-only barrier: leaves VMEM (publish stores / zi prefetch) in flight.
#define BAR_LGKM() do { \
  asm volatile("s_waitcnt lgkmcnt(0)" ::: "memory"); \
  __builtin_amdgcn_sched_barrier(0); \
  __builtin_amdgcn_s_barrier(); \
  __builtin_amdgcn_sched_barrier(0); \
} while (0)

// ---------------------------------------------------------------- K0: prep (unchanged)
__global__ __launch_bounds__(256) void k_prep(const float* __restrict__ W_in,
                                              const float* __restrict__ U,
                                              const float* __restrict__ V,
                                              const float* __restrict__ W_out,
                                              char* __restrict__ ws) {
  bf16* winb  = (bf16*)(ws + WIN_OFF);
  bf16* ub    = (bf16*)(ws + U_OFF);
  bf16* vb    = (bf16*)(ws + V_OFF);
  bf16* woutb = (bf16*)(ws + WOUT_OFF);
  bf16* qseq  = (bf16*)(ws + QSEQ_OFF);
  unsigned* flg = (unsigned*)(ws + FLAG_OFF);
  size_t id = (size_t)blockIdx.x * 256 + threadIdx.x;
  if      (id < 262144) winb[id]           = (bf16)W_in[id];
  else if (id < 393216) ub[id - 262144]    = (bf16)U[id - 262144];
  else if (id < 524288) vb[id - 393216]    = (bf16)V[id - 393216];
  else if (id < 786432) woutb[id - 524288] = (bf16)W_out[id - 524288];
  else if (id < 802816) qseq[id - 786432]  = (bf16)0.0f;   // q_0 = 0
  else if (id < 802848) flg[id - 802816]   = 0u;           // legacy
}

// ---------------------------------------------------------------- K1: zi = x @ W_in^T  (unchanged)
__global__ __launch_bounds__(256) void k_zi(const float* __restrict__ x,
                                            const char* __restrict__ ws,
                                            bf16* __restrict__ zi) {
  const bf16* winb = (const bf16*)(ws + WIN_OFF);
  __shared__ bf16 xl[128 * 264];
  __shared__ bf16 wl[128 * 264];
  const int tid = threadIdx.x, lane = tid & 63, wv = tid >> 6;
  const int q4 = lane >> 4, l16 = lane & 15;
  const int m0b = blockIdx.x * 128, n0 = blockIdx.y * 128;

  for (int ch = tid; ch < 8192; ch += 256) {
    int r = ch >> 6, c4 = ch & 63;
    float4 f = *(const float4*)&x[(size_t)(m0b + r) * 256 + c4 * 4];
    bf16x4 b; b[0] = (bf16)f.x; b[1] = (bf16)f.y; b[2] = (bf16)f.z; b[3] = (bf16)f.w;
    *(bf16x4*)&xl[r * 264 + c4 * 4] = b;
  }
  for (int ch = tid; ch < 4096; ch += 256) {
    int r = ch >> 5, c8 = ch & 31;
    *(uint4*)&wl[r * 264 + c8 * 8] = *(const uint4*)&winb[(size_t)(n0 + r) * 256 + c8 * 8];
  }
  __syncthreads();

  f32x4 z4 = {0.f, 0.f, 0.f, 0.f};
  f32x4 acc[2][8];
#pragma unroll
  for (int i = 0; i < 2; i++)
#pragma unroll
    for (int j = 0; j < 8; j++) acc[i][j] = z4;

  const int m0 = wv * 32;
#pragma unroll
  for (int kc = 0; kc < 8; kc++) {
    bf16x8 a0 = *(bf16x8*)&xl[(m0 + l16) * 264 + kc * 32 + q4 * 8];
    bf16x8 a1 = *(bf16x8*)&xl[(m0 + 16 + l16) * 264 + kc * 32 + q4 * 8];
#pragma unroll
    for (int nt = 0; nt < 8; nt++) {
      bf16x8 b = *(bf16x8*)&wl[(nt * 16 + l16) * 264 + kc * 32 + q4 * 8];
      acc[0][nt] = MFMA(a0, b, acc[0][nt]);
      acc[1][nt] = MFMA(a1, b, acc[1][nt]);
    }
  }
  __syncthreads();
#pragma unroll
  for (int mt = 0; mt < 2; mt++)
#pragma unroll
    for (int nt = 0; nt < 8; nt++)
#pragma unroll
      for (int r = 0; r < 4; r++) {
        int m = m0 + mt * 16 + q4 * 4 + r;
        int c = nt * 16 + l16;
        xl[m * 136 + c] = (bf16)acc[mt][nt][r];
      }
  __syncthreads();
  for (int ch = tid; ch < 2048; ch += 256) {
    int r = ch >> 4, c8 = ch & 15;
    *(uint4*)&zi[(size_t)(m0b + r) * 1024 + n0 + c8 * 8] = *(uint4*)&xl[r * 136 + c8 * 8];
  }
}

// ---------------------------------------------------------------- K1b: sentinel-fill partial slots
__global__ __launch_bounds__(256) void k_clr(char* __restrict__ ws) {
  u64* tp = (u64*)(ws + WIN_OFF);
  tp[(size_t)blockIdx.x * 256 + threadIdx.x] = SENT64;
}

// ---------------------------------------------------------------- K2: scan, sentinel protocol
// Identical to round 6 except the reduce spin: BATCHED retry rounds (all 8
// loads re-issued per round -> one memory latency per round) instead of eight
// serialized per-word dependent spin loops (round-6 lesson: 8x round trips).
__global__ __launch_bounds__(256) void k_scan(char* __restrict__ ws,
                                              const float* __restrict__ b_h) {
  const bf16* zi = (const bf16*)(ws + ZI_OFF);
  const bf16* ub = (const bf16*)(ws + U_OFF);
  const bf16* vb = (const bf16*)(ws + V_OFF);
  bf16* qseq = (bf16*)(ws + QSEQ_OFF);
  u64* tpb = (u64*)(ws + WIN_OFF);               // [3 slot][8 bg][4 g][512] u64

  __shared__ bf16 Vl[256 * 136];   // V[hcol0+r][rank]   69632 B
  __shared__ bf16 Ul[128 * 264];   // U[rank][hcol0+c]   67584 B
  __shared__ bf16 ql[16 * 136];    // q_t [row][rank]     4352 B
  __shared__ bf16 hl[16 * 264];    // h   [row][hcol]     8448 B
  // total 150016 B

  const int tid = threadIdx.x, lane = tid & 63, w = tid >> 6;   // 4 waves
  const int l16 = lane & 15, q4 = lane >> 4;
  const int bg = blockIdx.x & 7, g = blockIdx.x >> 3;
  const int brow0 = bg * 16, hcol0 = g * 256;

  // ---- stage weights (one-time, L2 -> LDS)
  for (int ch = tid; ch < 4096; ch += 256) {
    int r = ch >> 4, c8 = ch & 15;
    *(uint4*)&Vl[r * 136 + c8 * 8] = *(const uint4*)&vb[(size_t)(hcol0 + r) * 128 + c8 * 8];
  }
  for (int ch = tid; ch < 4096; ch += 256) {
    int r = ch >> 5, c8 = ch & 31;
    *(uint4*)&Ul[r * 264 + c8 * 8] = *(const uint4*)&ub[(size_t)r * 1024 + hcol0 + c8 * 8];
  }
  for (int i = tid; i < 16 * 136; i += 256) ql[i] = (bf16)0.0f;   // q_0 = 0

  // bias at stage2-transposed C-frag positions: hcol = w*64 + nt*16 + q4*4 + rr
  float bj[16];
#pragma unroll
  for (int nt = 0; nt < 4; nt++)
#pragma unroll
    for (int rr = 0; rr < 4; rr++)
      bj[nt * 4 + rr] = b_h[hcol0 + w * 64 + nt * 16 + q4 * 4 + rr];

  // zi at stage2-transposed C-frag positions: row = brow0+l16, 4 consecutive cols -> u64
  B4U zc[4], zn[4];
#pragma unroll
  for (int nt = 0; nt < 4; nt++)
    zc[nt].u = *(const u64*)&zi[(size_t)(brow0 + l16) * 1024 + hcol0 + w * 64 + nt * 16 + q4 * 4];
  __syncthreads();

  const f32x4 z4 = {0.f, 0.f, 0.f, 0.f};

  for (int t = 0; t < TSTEPS - 1; t++) {
    // drain prev-step publish + clear stores BEFORE issuing this step's stores
    asm volatile("s_waitcnt vmcnt(0)" ::: "memory");
    __builtin_amdgcn_sched_barrier(0);

    // prefetch zi[t+1] (plain cached u64 loads; consumed at step end)
#pragma unroll
    for (int nt = 0; nt < 4; nt++)
      zn[nt].u = *(const u64*)&zi[((size_t)(t + 1) * NBATCH + brow0 + l16) * 1024 +
                                  hcol0 + w * 64 + nt * 16 + q4 * 4];

    // ---- stage2 (TRANSPOSED): zh^T[hcol][batch] = V_g @ q_t^T  (K=128)
    f32x4 az[4] = {z4, z4, z4, z4};
#pragma unroll
    for (int kc = 0; kc < 4; kc++) {
      bf16x8 qf = *(const bf16x8*)&ql[l16 * 136 + kc * 32 + q4 * 8];
#pragma unroll
      for (int nt = 0; nt < 4; nt++) {
        bf16x8 vf = *(const bf16x8*)&Vl[(w * 64 + nt * 16 + l16) * 136 + kc * 32 + q4 * 8];
        az[nt] = MFMA(vf, qf, az[nt]);
      }
    }
    // h = relu(zh + b + zi): 4 consecutive hcols -> one ds_write_b64 per nt
#pragma unroll
    for (int nt = 0; nt < 4; nt++) {
      bf16x4 hv;
#pragma unroll
      for (int rr = 0; rr < 4; rr++) {
        float v = az[nt][rr] + bj[nt * 4 + rr] + (float)zc[nt].b[rr];
        hv[rr] = (bf16)fmaxf(v, 0.0f);
      }
      *(bf16x4*)&hl[l16 * 264 + w * 64 + nt * 16 + q4 * 4] = hv;
    }
    BAR_LGKM();   // hl ready; ql fully consumed

    // ---- stage1 (TRANSPOSED): P[rank][batch] = U_slice @ h^T  (K=256)
    f32x4 ap[2] = {z4, z4};
#pragma unroll
    for (int kc = 0; kc < 8; kc++) {
      bf16x8 hf = *(const bf16x8*)&hl[l16 * 264 + kc * 32 + q4 * 8];
#pragma unroll
      for (int mt = 0; mt < 2; mt++) {
        bf16x8 uf = *(const bf16x8*)&Ul[(w * 32 + mt * 16 + l16) * 264 + kc * 32 + q4 * 8];
        ap[mt] = MFMA(uf, hf, ap[mt]);
      }
    }

    // ---- publish partial (fire-and-forget) to slot (t+1)%3
    const int s1 = (t + 1) % 3;
    u64* myp = &tpb[(size_t)((s1 * NBG + bg) * NGH + g) * 512];
#pragma unroll
    for (int mt = 0; mt < 2; mt++) {
      B4U pk;
      pk.b[0] = (bf16)ap[mt][0]; pk.b[1] = (bf16)ap[mt][1];
      pk.b[2] = (bf16)ap[mt][2]; pk.b[3] = (bf16)ap[mt][3];
      cstore64(&myp[l16 * 32 + w * 8 + mt * 4 + q4], pk.u);
    }

    // ---- reduce: BATCHED spin. Each round issues all 8 independent loads,
    // one s_waitcnt, 8 checks -> one memory latency per round (not 8).
    const u64* rb = &tpb[(size_t)(s1 * NBG + bg) * NGH * 512];
    u64 vv[8];
#pragma unroll
    for (int pp = 0; pp < 4; pp++) {
      vv[pp * 2]     = cload64(&rb[(size_t)pp * 512 + tid * 2]);
      vv[pp * 2 + 1] = cload64(&rb[(size_t)pp * 512 + tid * 2 + 1]);
    }
    while (issent(vv[0]) | issent(vv[1]) | issent(vv[2]) | issent(vv[3]) |
           issent(vv[4]) | issent(vv[5]) | issent(vv[6]) | issent(vv[7])) {
#pragma unroll
      for (int pp = 0; pp < 4; pp++) {
        vv[pp * 2]     = cload64(&rb[(size_t)pp * 512 + tid * 2]);
        vv[pp * 2 + 1] = cload64(&rb[(size_t)pp * 512 + tid * 2 + 1]);
      }
    }

    float s[8] = {0.f, 0.f, 0.f, 0.f, 0.f, 0.f, 0.f, 0.f};
#pragma unroll
    for (int pp = 0; pp < 4; pp++)
#pragma unroll
      for (int i = 0; i < 2; i++) {
        u64 u = vv[pp * 2 + i];
        s[i * 4 + 0] += bfbits((u32)(u & 0xFFFFu));
        s[i * 4 + 1] += bfbits((u32)((u >> 16) & 0xFFFFu));
        s[i * 4 + 2] += bfbits((u32)((u >> 32) & 0xFFFFu));
        s[i * 4 + 3] += bfbits((u32)(u >> 48));
      }

    // ---- install q_{t+1} into ql (+ qseq by g==0)
    union { bf16x8 v; uint4 u4; } qv;
#pragma unroll
    for (int k = 0; k < 8; k++) qv.v[k] = (bf16)s[k];
    *(bf16x8*)&ql[(tid >> 4) * 136 + (tid & 15) * 8] = qv.v;
    if (g == 0)
      *(uint4*)&qseq[((size_t)(t + 1) * NBATCH + brow0 + (tid >> 4)) * NRANK + (tid & 15) * 8] = qv.u4;

    // ---- re-sentinel own slot t%3 (spin success proved all consumed q(t))
    const int s0 = t % 3;
    u64* myc = &tpb[(size_t)((s0 * NBG + bg) * NGH + g) * 512];
    cstore64(&myc[tid * 2],     SENT64);
    cstore64(&myc[tid * 2 + 1], SENT64);

    BAR_LGKM();   // ql ready for next stage2; hl free for overwrite

#pragma unroll
    for (int nt = 0; nt < 4; nt++) zc[nt] = zn[nt];
  }
}

// ---------------------------------------------------------------- K3: hidden[t] = relu(q_t V^T + b + zi_t)  (unchanged)
__global__ __launch_bounds__(256) void k_hidden(const char* __restrict__ ws,
                                                const float* __restrict__ b_h,
                                                float* __restrict__ hid) {
  const bf16* qseq = (const bf16*)(ws + QSEQ_OFF);
  const bf16* vb   = (const bf16*)(ws + V_OFF);
  const bf16* zi   = (const bf16*)(ws + ZI_OFF);
  const int t = blockIdx.x, n0 = blockIdx.y * 128;
  const int tid = threadIdx.x, lane = tid & 63, wv = tid >> 6;
  const int q4 = lane >> 4, l16 = lane & 15;

  __shared__ bf16 ql2[128 * 136];
  __shared__ bf16 vl2[128 * 136];
  __shared__ bf16 zl2[128 * 136];
  __shared__ float bl2[128];

  for (int ch = tid; ch < 2048; ch += 256) {
    int r = ch >> 4, c8 = ch & 15;
    *(uint4*)&ql2[r * 136 + c8 * 8] = *(const uint4*)&qseq[(size_t)t * 16384 + r * 128 + c8 * 8];
    *(uint4*)&vl2[r * 136 + c8 * 8] = *(const uint4*)&vb[(size_t)(n0 + r) * 128 + c8 * 8];
    *(uint4*)&zl2[r * 136 + c8 * 8] = *(const uint4*)&zi[((size_t)t * 128 + r) * 1024 + n0 + c8 * 8];
  }
  if (tid < 128) bl2[tid] = b_h[n0 + tid];
  __syncthreads();

  f32x4 z4 = {0.f, 0.f, 0.f, 0.f};
  f32x4 acc[2][8];
#pragma unroll
  for (int i = 0; i < 2; i++)
#pragma unroll
    for (int j = 0; j < 8; j++) acc[i][j] = z4;

  const int m0 = wv * 32;
#pragma unroll
  for (int kc = 0; kc < 4; kc++) {
    bf16x8 a0 = *(bf16x8*)&ql2[(m0 + l16) * 136 + kc * 32 + q4 * 8];
    bf16x8 a1 = *(bf16x8*)&ql2[(m0 + 16 + l16) * 136 + kc * 32 + q4 * 8];
#pragma unroll
    for (int nt = 0; nt < 8; nt++) {
      bf16x8 b = *(bf16x8*)&vl2[(nt * 16 + l16) * 136 + kc * 32 + q4 * 8];
      acc[0][nt] = MFMA(a0, b, acc[0][nt]);
      acc[1][nt] = MFMA(a1, b, acc[1][nt]);
    }
  }
#pragma unroll
  for (int mt = 0; mt < 2; mt++)
#pragma unroll
    for (int nt = 0; nt < 8; nt++)
#pragma unroll
      for (int r = 0; r < 4; r++) {
        int m = m0 + mt * 16 + q4 * 4 + r;
        int c = nt * 16 + l16;
        float v = acc[mt][nt][r] + bl2[c] + (float)zl2[m * 136 + c];
        hid[((size_t)t * 128 + m) * 1024 + n0 + c] = fmaxf(v, 0.0f);
      }
}

// ---------------------------------------------------------------- K4: output = hidden @ W_out^T + b_out (unchanged)
__global__ __launch_bounds__(512) void k_out(const char* __restrict__ ws,
                                             const float* __restrict__ hid,
                                             const float* __restrict__ b_out,
                                             float* __restrict__ out) {
  const bf16* woutb = (const bf16*)(ws + WOUT_OFF);
  const int t = blockIdx.x;
  const int tid = threadIdx.x, lane = tid & 63, wv = tid >> 6;  // 8 waves
  const int q4 = lane >> 4, l16 = lane & 15;

  __shared__ bf16 hl2[128 * 136];
  __shared__ bf16 wl2[256 * 136];
  __shared__ float bol[256];
  if (tid < 256) bol[tid] = b_out[tid];

  f32x4 z4 = {0.f, 0.f, 0.f, 0.f};
  f32x4 acc[16];
#pragma unroll
  for (int j = 0; j < 16; j++) acc[j] = z4;

  const int m0 = wv * 16;
  for (int k0 = 0; k0 < 1024; k0 += 128) {
    __syncthreads();
    for (int ch = tid; ch < 4096; ch += 512) {
      int r = ch >> 5, c4 = ch & 31;
      float4 f = *(const float4*)&hid[((size_t)t * 128 + r) * 1024 + k0 + c4 * 4];
      bf16x4 b; b[0] = (bf16)f.x; b[1] = (bf16)f.y; b[2] = (bf16)f.z; b[3] = (bf16)f.w;
      *(bf16x4*)&hl2[r * 136 + c4 * 4] = b;
    }
    for (int ch = tid; ch < 4096; ch += 512) {
      int r = ch >> 4, c8 = ch & 15;
      *(uint4*)&wl2[r * 136 + c8 * 8] = *(const uint4*)&woutb[(size_t)r * 1024 + k0 + c8 * 8];
    }
    __syncthreads();
#pragma unroll
    for (int kc = 0; kc < 4; kc++) {
      bf16x8 a = *(bf16x8*)&hl2[(m0 + l16) * 136 + kc * 32 + q4 * 8];
#pragma unroll
      for (int nt = 0; nt < 16; nt++) {
        bf16x8 b = *(bf16x8*)&wl2[(nt * 16 + l16) * 136 + kc * 32 + q4 * 8];
        acc[nt] = MFMA(a, b, acc[nt]);
      }
    }
  }
#pragma unroll
  for (int nt = 0; nt < 16; nt++)
#pragma unroll
    for (int r = 0; r < 4; r++) {
      int m = m0 + q4 * 4 + r;
      int c = nt * 16 + l16;
      out[((size_t)t * 128 + m) * 256 + c] = acc[nt][r] + bol[c];
    }
}

// ---------------------------------------------------------------- launch
extern "C" void kernel_launch(void* const* d_in, const int* in_sizes, int n_in,
                              void* d_out, int out_size, void* d_ws, size_t ws_size,
                              hipStream_t stream) {
  (void)in_sizes; (void)n_in; (void)out_size; (void)ws_size;
  const float* x     = (const float*)d_in[0];
  const float* W_in  = (const float*)d_in[1];
  const float* U     = (const float*)d_in[2];
  const float* V     = (const float*)d_in[3];
  const float* b_h   = (const float*)d_in[4];
  const float* W_out = (const float*)d_in[5];
  const float* b_out = (const float*)d_in[6];
  char* ws = (char*)d_ws;
  float* hid = (float*)d_out;
  float* out = hid + (size_t)TSTEPS * NBATCH * DH;
  bf16* zi = (bf16*)(ws + ZI_OFF);

  k_prep<<<dim3(3137), dim3(256), 0, stream>>>(W_in, U, V, W_out, ws);
  k_zi<<<dim3(512, 8), dim3(256), 0, stream>>>(x, ws, zi);
  k_clr<<<dim3(192), dim3(256), 0, stream>>>(ws);
  k_scan<<<dim3(NBG * NGH), dim3(256), 0, stream>>>(ws, b_h);
  k_hidden<<<dim3(512, 8), dim3(256), 0, stream>>>(ws, b_h, hid);
  k_out<<<dim3(512), dim3(512), 0, stream>>>(ws, hid, b_out, out);
}